// Round 3
// baseline (185.113 us; speedup 1.0000x reference)
//
#include <hip/hip_runtime.h>
#include <math.h>

#define IMG_H 512
#define IMG_W 512
#define IMG_HW (IMG_H * IMG_W)

namespace {

// float32-rounded cos(k*pi/16) values
constexpr float CFv[9] = {
    1.0f,
    0.98078528040323044913f,
    0.92387953251128675613f,
    0.83146961230254523708f,
    0.70710678118654752440f,
    0.55557023301960222474f,
    0.38268343236508977173f,
    0.19509032201612826785f,
    0.0f
};

struct CTab {
    float  cf[8][8];     // C[x][u] = f32(cos((2x+1)u pi/16))
    double cd[8][8];     // promoted to double
    float  aof[8][8];    // ALPHA outer product (f32)
    float  scalef[8][8]; // DCT_SCALE = ALPHA*0.25
};

constexpr CTab make_ctab() {
    CTab t{};
    for (int y = 0; y < 8; y++) {
        for (int v = 0; v < 8; v++) {
            int a = ((2 * y + 1) * v) & 31;
            if (a > 16) a = 32 - a;
            float val = (a <= 8) ? CFv[a] : -CFv[16 - a];
            t.cf[y][v] = val;
            t.cd[y][v] = (double)val;
        }
    }
    constexpr float A0 = 0.70710678118654752440f;
    for (int u = 0; u < 8; u++) {
        for (int v = 0; v < 8; v++) {
            float au = (u == 0) ? A0 : 1.0f;
            float av = (v == 0) ? A0 : 1.0f;
            float ao = au * av;
            t.aof[u][v] = ao;
            t.scalef[u][v] = ao * 0.25f;
        }
    }
    return t;
}

constexpr CTab CT = make_ctab();

// color coefficients: f32-rounded, promoted to double, 255 folded in
constexpr double YC0 = (double)0.299f    * 255.0;
constexpr double YC1 = (double)0.587f    * 255.0;
constexpr double YC2 = (double)0.114f    * 255.0;
constexpr double CB0 = (double)-0.168736f * 255.0;
constexpr double CB1 = (double)-0.331264f * 255.0;
constexpr double CB2 = (double)0.5f      * 255.0;
constexpr double CR0 = (double)0.5f      * 255.0;
constexpr double CR1 = (double)-0.418688f * 255.0;
constexpr double CR2 = (double)-0.081312f * 255.0;

// ---- LDS layout (bytes) ----------------------------------------------------
// lY   double[16*66] @0       8448   (Y-128, stride 66 doubles)
//   overlay after B2: yR f32[16*66]@0, cbR f32[8*34]@4224, crR f32[8*34]@5312
// cbP  double[8*34]  @8448    2176   (centered chroma, pooled)
// crP  double[8*34]  @10624   2176
// qY   double[144]   @12800   1152   ([v*18+2u]=fs, +1=ds)
// qC   double[144]   @13952   1152
#define OFF_CBP 8448
#define OFF_CRP 10624
#define OFF_QY  12800
#define OFF_QC  13952
#define SMEM_BYTES 15104

__device__ __forceinline__ void xpose8_d(double v[8]) {
    const int l = threadIdx.x & 7;
    #pragma unroll
    for (int m = 1; m < 8; m <<= 1) {
        #pragma unroll
        for (int k = 0; k < 8; k++) {
            if ((k & m) == 0) {
                const int kp = k | m;
                double send = (l & m) ? v[k] : v[kp];
                double recv = __shfl_xor(send, m);
                v[k]  = (l & m) ? recv : v[k];
                v[kp] = (l & m) ? v[kp] : recv;
            }
        }
    }
}

__device__ __forceinline__ void xpose8_f(float v[8]) {
    const int l = threadIdx.x & 7;
    #pragma unroll
    for (int m = 1; m < 8; m <<= 1) {
        #pragma unroll
        for (int k = 0; k < 8; k++) {
            if ((k & m) == 0) {
                const int kp = k | m;
                float send = (l & m) ? v[k] : v[kp];
                float recv = __shfl_xor(send, m);
                v[k]  = (l & m) ? recv : v[k];
                v[kp] = (l & m) ? v[kp] : recv;
            }
        }
    }
}

} // namespace

__global__ void __launch_bounds__(256, 6) djpeg_kernel(
    const float* __restrict__ img,
    const float* __restrict__ ytab,
    const float* __restrict__ ctab,
    float* __restrict__ out)
{
    __shared__ __align__(16) unsigned char smem[SMEM_BYTES];
    double* lY  = (double*)(smem);
    double* cbP = (double*)(smem + OFF_CBP);
    double* crP = (double*)(smem + OFF_CRP);
    double* qY  = (double*)(smem + OFF_QY);
    double* qC  = (double*)(smem + OFF_QC);
    // fp32 overlays of the lY region (dead after stage-A reads / B2)
    float* yR  = (float*)(smem);
    float* cbR = (float*)(smem + 4224);
    float* crR = (float*)(smem + 5312);

    const int t  = threadIdx.x;
    const int X0 = blockIdx.x * 64;
    const int Y0 = blockIdx.y * 16;
    const int bi = blockIdx.z;

    // ---- quant factors (fp64; table*0.4 in f32 per weak-scalar promotion)
    if (t < 128) {
        const float* tab = (t < 64) ? ytab : ctab;
        double* q = (t < 64) ? qY : qC;
        int e = t & 63, u = e >> 3, v = e & 7;
        float tfacf = tab[e] * 0.4f;
        double tf = (double)tfacf;
        q[v * 18 + 2 * u]     = (double)CT.scalef[u][v] / tf;  // fs
        q[v * 18 + 2 * u + 1] = tf * (double)CT.aof[u][v];     // ds (includes ALPHA)
    }

    // ---- phase 1: load RGB, centered YCbCr (fp64), Y-128 -> LDS, pooled chroma -> LDS
    {
        const int x = t & 63, yb = t >> 6;
        double accb[2] = {0.0, 0.0}, accr[2] = {0.0, 0.0};
        size_t base = ((size_t)bi * 3) * IMG_HW + (size_t)Y0 * IMG_W + X0 + x;
        #pragma unroll
        for (int i = 0; i < 4; i++) {
            int y = yb * 4 + i;
            size_t p = base + (size_t)y * IMG_W;
            double R = (double)img[p];
            double G = (double)img[p + IMG_HW];
            double B = (double)img[p + 2 * IMG_HW];
            double Yv = YC0 * R + YC1 * G + YC2 * B - 128.0;  // Y - 128
            double Cb = CB0 * R + CB1 * G + CB2 * B;          // centered Cb
            double Cr = CR0 * R + CR1 * G + CR2 * B;          // centered Cr
            lY[y * 66 + x] = Yv;
            accb[i >> 1] += Cb;
            accr[i >> 1] += Cr;
        }
        #pragma unroll
        for (int p2 = 0; p2 < 2; p2++) {
            double hb = accb[p2] + __shfl_xor(accb[p2], 1);
            double hr = accr[p2] + __shfl_xor(accr[p2], 1);
            if ((x & 1) == 0) {
                int pr = yb * 2 + p2;
                cbP[pr * 34 + (x >> 1)] = hb * 0.25;
                crP[pr * 34 + (x >> 1)] = hr * 0.25;
            }
        }
    }
    __syncthreads();  // B1

    // ---- DCT pipeline: 24 blocks x 8 lanes (t<192), in-register transposes
    const bool act = (t < 192);
    const int r = t & 7;
    const double* src = lY;
    const double* qtab = qY;
    float* dstR = yR;
    if (act) {
        if (t < 128) {                 // 16 Y blocks
            int g = t >> 3, by = g >> 3, bx = g & 7;
            src  = lY + (by * 8 + r) * 66 + bx * 8;
            dstR = yR + (by * 8 + r) * 66 + bx * 8;
            qtab = qY;
        } else {
            int c = t - 128;
            int isCr = c >> 5;
            int g2 = (c >> 3) & 3;
            src  = (isCr ? crP : cbP) + r * 34 + g2 * 8;
            dstR = (isCr ? crR : cbR) + r * 34 + g2 * 8;
            qtab = qC;
        }
    }
    const float addv = (t < 128) ? 128.0f : 0.0f;  // wave-uniform

    double s1[8];
    if (act) {
        // stage A: forward row pass, even/odd symmetry (fp64)
        double a[8];
        #pragma unroll
        for (int y = 0; y < 8; y++) a[y] = src[y];   // already centered
        double e[4], o[4];
        #pragma unroll
        for (int i = 0; i < 4; i++) { e[i] = a[i] + a[7 - i]; o[i] = a[i] - a[7 - i]; }
        #pragma unroll
        for (int v = 0; v < 8; v += 2) {
            s1[v]     = e[0] * CT.cd[0][v]     + e[1] * CT.cd[1][v]     + e[2] * CT.cd[2][v]     + e[3] * CT.cd[3][v];
            s1[v + 1] = o[0] * CT.cd[0][v + 1] + o[1] * CT.cd[1][v + 1] + o[2] * CT.cd[2][v + 1] + o[3] * CT.cd[3][v + 1];
        }
        xpose8_d(s1);   // lane r now holds s1[x] for column v=r
    }

    float mrow[8];
    if (act) {
        // stage B: forward col pass (even/odd) + quant + diff_round + dequant
        double e[4], o[4];
        #pragma unroll
        for (int i = 0; i < 4; i++) { e[i] = s1[i] + s1[7 - i]; o[i] = s1[i] - s1[7 - i]; }
        double D[8];
        #pragma unroll
        for (int u = 0; u < 8; u += 2) {
            D[u]     = e[0] * CT.cd[0][u]     + e[1] * CT.cd[1][u]     + e[2] * CT.cd[2][u]     + e[3] * CT.cd[3][u];
            D[u + 1] = o[0] * CT.cd[0][u + 1] + o[1] * CT.cd[1][u + 1] + o[2] * CT.cd[2][u + 1] + o[3] * CT.cd[3][u + 1];
        }
        float dq[8];
        #pragma unroll
        for (int u = 0; u < 8; u++) {
            double fs = qtab[r * 18 + 2 * u];
            double ds = qtab[r * 18 + 2 * u + 1];
            double xq = D[u] * fs;
            double rq = rint(xq);
            double ee = xq - rq;
            dq[u] = (float)((rq + ee * ee * ee) * ds);
        }
        // stage C: IDCT over u (fp32, even/odd): m[x] = sum_u dq[u]*C[x][u]
        #pragma unroll
        for (int x = 0; x < 4; x++) {
            float E = dq[0] * CT.cf[x][0] + dq[2] * CT.cf[x][2] + dq[4] * CT.cf[x][4] + dq[6] * CT.cf[x][6];
            float O = dq[1] * CT.cf[x][1] + dq[3] * CT.cf[x][3] + dq[5] * CT.cf[x][5] + dq[7] * CT.cf[x][7];
            mrow[x]     = E + O;
            mrow[7 - x] = E - O;
        }
        xpose8_f(mrow);  // lane r now holds m[x=r][v=0..7]
    }

    __syncthreads();  // B2: staging reads done; overlay becomes writable

    if (act) {
        // stage D: IDCT over v (fp32, even/odd), write spatial row r
        #pragma unroll
        for (int y = 0; y < 4; y++) {
            float E = mrow[0] * CT.cf[y][0] + mrow[2] * CT.cf[y][2] + mrow[4] * CT.cf[y][4] + mrow[6] * CT.cf[y][6];
            float O = mrow[1] * CT.cf[y][1] + mrow[3] * CT.cf[y][3] + mrow[5] * CT.cf[y][5] + mrow[7] * CT.cf[y][7];
            dstR[y]     = 0.25f * (E + O) + addv;   // Y rows carry +128; chroma stays centered
            dstR[7 - y] = 0.25f * (E - O) + addv;
        }
    }
    __syncthreads();  // B3

    // ---- phase 3: upsample chroma (centered), YCbCr->RGB, clip, /255, store
    {
        const int x = t & 63, yb = t >> 6;
        size_t base = ((size_t)bi * 3) * IMG_HW + (size_t)Y0 * IMG_W + X0 + x;
        #pragma unroll
        for (int i = 0; i < 4; i++) {
            int y = yb * 4 + i;
            float Yv = yR[y * 66 + x];
            float Cb = cbR[(y >> 1) * 34 + (x >> 1)];
            float Cr = crR[(y >> 1) * 34 + (x >> 1)];
            float Rr = fmaf(1.402f, Cr, Yv);
            float Gg = Yv - 0.344136f * Cb - 0.714136f * Cr;
            float Bb = fmaf(1.772f, Cb, Yv);
            Rr = fminf(fmaxf(Rr, 0.0f), 255.0f) * (1.0f / 255.0f);
            Gg = fminf(fmaxf(Gg, 0.0f), 255.0f) * (1.0f / 255.0f);
            Bb = fminf(fmaxf(Bb, 0.0f), 255.0f) * (1.0f / 255.0f);
            size_t p = base + (size_t)y * IMG_W;
            out[p] = Rr;
            out[p + IMG_HW] = Gg;
            out[p + 2 * IMG_HW] = Bb;
        }
    }
}

extern "C" void kernel_launch(void* const* d_in, const int* in_sizes, int n_in,
                              void* d_out, int out_size, void* d_ws, size_t ws_size,
                              hipStream_t stream) {
    (void)n_in; (void)out_size; (void)d_ws; (void)ws_size;
    const float* img = (const float*)d_in[0];
    const float* yt  = (const float*)d_in[1];
    const float* ct  = (const float*)d_in[2];
    float* out = (float*)d_out;
    int B = in_sizes[0] / (3 * IMG_HW);   // 32
    dim3 grid(IMG_W / 64, IMG_H / 16, B); // (8, 32, 32)
    djpeg_kernel<<<grid, dim3(256, 1, 1), 0, stream>>>(img, yt, ct, out);
}